// Round 1
// baseline (8282.498 us; speedup 1.0000x reference)
//
#include <hip/hip_runtime.h>

#define NN 100000
#define NE 600000

typedef float v4 __attribute__((ext_vector_type(4)));

// ---------------------------------------------------------------------------
// Edge kernel: h = relu([x[col],ea] @ W1a + b1a) @ W1b + b1b ; atomic scatter
// 2 edges per thread (shares W1b LDS broadcast reads).
// ---------------------------------------------------------------------------
__global__ __launch_bounds__(256) void edge_kernel(
    const float* __restrict__ x, const int* __restrict__ edge_index,
    const float* __restrict__ edge_attr,
    const float* __restrict__ W1a, const float* __restrict__ b1a,
    const float* __restrict__ W1b, const float* __restrict__ b1b,
    float* __restrict__ s, float* __restrict__ cnt)
{
    __shared__ float w1a[256];
    __shared__ float ba[64];
    __shared__ float w1b[8192];
    __shared__ float bb[128];
    const int tid = threadIdx.x;

    w1a[tid] = W1a[tid];
    if (tid < 64)  ba[tid] = b1a[tid];
    if (tid < 128) bb[tid] = b1b[tid];
    for (int i = tid * 4; i < 8192; i += 1024)
        *(v4*)&w1b[i] = *(const v4*)&W1b[i];
    __syncthreads();

    const int e0 = blockIdx.x * 512 + tid;
    const int e1 = e0 + 256;
    const bool a0 = e0 < NE;
    const bool a1 = e1 < NE;

    int rowA = 0, rowB = 0;
    float inA[4] = {0.f, 0.f, 0.f, 0.f};
    float inB[4] = {0.f, 0.f, 0.f, 0.f};
    if (a0) {
        rowA = edge_index[e0];
        int col = edge_index[NE + e0];
        inA[0] = x[col * 2 + 0]; inA[1] = x[col * 2 + 1];
        inA[2] = edge_attr[e0 * 2 + 0]; inA[3] = edge_attr[e0 * 2 + 1];
    }
    if (a1) {
        rowB = edge_index[e1];
        int col = edge_index[NE + e1];
        inB[0] = x[col * 2 + 0]; inB[1] = x[col * 2 + 1];
        inB[2] = edge_attr[e1 * 2 + 0]; inB[3] = edge_attr[e1 * 2 + 1];
    }

    float h1a[64], h1b[64];
#pragma unroll
    for (int jg = 0; jg < 16; ++jg) {
        v4 r0 = *(const v4*)&w1a[jg * 4];
        v4 r1 = *(const v4*)&w1a[64 + jg * 4];
        v4 r2 = *(const v4*)&w1a[128 + jg * 4];
        v4 r3 = *(const v4*)&w1a[192 + jg * 4];
        v4 b4 = *(const v4*)&ba[jg * 4];
#pragma unroll
        for (int m = 0; m < 4; ++m) {
            float va = b4[m] + inA[0]*r0[m] + inA[1]*r1[m] + inA[2]*r2[m] + inA[3]*r3[m];
            float vb = b4[m] + inB[0]*r0[m] + inB[1]*r1[m] + inB[2]*r2[m] + inB[3]*r3[m];
            h1a[jg * 4 + m] = fmaxf(va, 0.f);
            h1b[jg * 4 + m] = fmaxf(vb, 0.f);
        }
    }

    float* srowA = s + (size_t)rowA * 128;
    float* srowB = s + (size_t)rowB * 128;
    for (int cg = 0; cg < 32; ++cg) {
        v4 b4 = *(const v4*)&bb[cg * 4];
        v4 accA = b4, accB = b4;
#pragma unroll
        for (int k = 0; k < 64; ++k) {
            v4 w = *(const v4*)&w1b[k * 128 + cg * 4];
            accA += h1a[k] * w;
            accB += h1b[k] * w;
        }
        if (a0) {
            atomicAdd(&srowA[cg * 4 + 0], accA[0]);
            atomicAdd(&srowA[cg * 4 + 1], accA[1]);
            atomicAdd(&srowA[cg * 4 + 2], accA[2]);
            atomicAdd(&srowA[cg * 4 + 3], accA[3]);
        }
        if (a1) {
            atomicAdd(&srowB[cg * 4 + 0], accB[0]);
            atomicAdd(&srowB[cg * 4 + 1], accB[1]);
            atomicAdd(&srowB[cg * 4 + 2], accB[2]);
            atomicAdd(&srowB[cg * 4 + 3], accB[3]);
        }
    }
    if (a0) atomicAdd(&cnt[rowA], 1.0f);
    if (a1) atomicAdd(&cnt[rowB], 1.0f);
}

// ---------------------------------------------------------------------------
// Node kernel: z = [x, s/max(cnt,1), u[batch]]; out = relu(z@W2a+b2a)@W2b+b2b
// 32 nodes per block, 256 threads. fp32 register tiling.
// ---------------------------------------------------------------------------
__global__ __launch_bounds__(256) void node_kernel(
    const float* __restrict__ x, const float* __restrict__ u,
    const int* __restrict__ batch,
    const float* __restrict__ s, const float* __restrict__ cnt,
    const float* __restrict__ W2a, const float* __restrict__ b2a,
    const float* __restrict__ W2b, const float* __restrict__ b2b,
    float* __restrict__ out)
{
    __shared__ float zs[32][136];   // 132 used, padded for alignment/banks
    __shared__ float ts[32][260];   // 256 used
    const int tid = threadIdx.x;
    const int node0 = blockIdx.x * 32;

    // Phase A: build z tile
    for (int idx = tid; idx < 32 * 132; idx += 256) {
        int r = idx / 132;
        int k = idx - r * 132;
        int node = node0 + r;
        float v;
        if (k < 2) {
            v = x[node * 2 + k];
        } else if (k < 130) {
            float c = fmaxf(cnt[node], 1.0f);
            v = s[(size_t)node * 128 + (k - 2)] * __frcp_rn(c);
        } else {
            v = u[batch[node] * 2 + (k - 130)];
        }
        zs[r][k] = v;
    }
    __syncthreads();

    const int tx = tid & 31;
    const int ty = tid >> 5;

    // Phase B: t = relu(z @ W2a + b2a)  -> ts   (4 nodes x 8 cols / thread)
    {
        float acc[4][8];
#pragma unroll
        for (int j = 0; j < 8; ++j) {
            float bj = b2a[tx * 8 + j];
            acc[0][j] = bj; acc[1][j] = bj; acc[2][j] = bj; acc[3][j] = bj;
        }
        for (int k = 0; k < 132; k += 4) {
            v4 z0 = *(const v4*)&zs[ty * 4 + 0][k];
            v4 z1 = *(const v4*)&zs[ty * 4 + 1][k];
            v4 z2 = *(const v4*)&zs[ty * 4 + 2][k];
            v4 z3 = *(const v4*)&zs[ty * 4 + 3][k];
#pragma unroll
            for (int kk = 0; kk < 4; ++kk) {
                v4 w0 = *(const v4*)&W2a[(k + kk) * 256 + tx * 8];
                v4 w1 = *(const v4*)&W2a[(k + kk) * 256 + tx * 8 + 4];
#pragma unroll
                for (int j = 0; j < 4; ++j) {
                    acc[0][j]     += z0[kk] * w0[j];
                    acc[1][j]     += z1[kk] * w0[j];
                    acc[2][j]     += z2[kk] * w0[j];
                    acc[3][j]     += z3[kk] * w0[j];
                    acc[0][j + 4] += z0[kk] * w1[j];
                    acc[1][j + 4] += z1[kk] * w1[j];
                    acc[2][j + 4] += z2[kk] * w1[j];
                    acc[3][j + 4] += z3[kk] * w1[j];
                }
            }
        }
#pragma unroll
        for (int i = 0; i < 4; ++i) {
            v4 o0, o1;
#pragma unroll
            for (int j = 0; j < 4; ++j) {
                o0[j] = fmaxf(acc[i][j], 0.f);
                o1[j] = fmaxf(acc[i][j + 4], 0.f);
            }
            *(v4*)&ts[ty * 4 + i][tx * 8] = o0;
            *(v4*)&ts[ty * 4 + i][tx * 8 + 4] = o1;
        }
    }
    __syncthreads();

    // Phase C: out = ts @ W2b + b2b   (4 nodes x 16 cols / thread)
    {
        float acc[4][16];
#pragma unroll
        for (int j = 0; j < 16; ++j) {
            float bj = b2b[tx * 16 + j];
            acc[0][j] = bj; acc[1][j] = bj; acc[2][j] = bj; acc[3][j] = bj;
        }
        for (int k = 0; k < 256; k += 4) {
            v4 z0 = *(const v4*)&ts[ty * 4 + 0][k];
            v4 z1 = *(const v4*)&ts[ty * 4 + 1][k];
            v4 z2 = *(const v4*)&ts[ty * 4 + 2][k];
            v4 z3 = *(const v4*)&ts[ty * 4 + 3][k];
#pragma unroll
            for (int kk = 0; kk < 4; ++kk) {
                v4 w0 = *(const v4*)&W2b[(k + kk) * 512 + tx * 16];
                v4 w1 = *(const v4*)&W2b[(k + kk) * 512 + tx * 16 + 4];
                v4 w2 = *(const v4*)&W2b[(k + kk) * 512 + tx * 16 + 8];
                v4 w3 = *(const v4*)&W2b[(k + kk) * 512 + tx * 16 + 12];
#pragma unroll
                for (int j = 0; j < 4; ++j) {
                    acc[0][j]      += z0[kk] * w0[j];
                    acc[1][j]      += z1[kk] * w0[j];
                    acc[2][j]      += z2[kk] * w0[j];
                    acc[3][j]      += z3[kk] * w0[j];
                    acc[0][j + 4]  += z0[kk] * w1[j];
                    acc[1][j + 4]  += z1[kk] * w1[j];
                    acc[2][j + 4]  += z2[kk] * w1[j];
                    acc[3][j + 4]  += z3[kk] * w1[j];
                    acc[0][j + 8]  += z0[kk] * w2[j];
                    acc[1][j + 8]  += z1[kk] * w2[j];
                    acc[2][j + 8]  += z2[kk] * w2[j];
                    acc[3][j + 8]  += z3[kk] * w2[j];
                    acc[0][j + 12] += z0[kk] * w3[j];
                    acc[1][j + 12] += z1[kk] * w3[j];
                    acc[2][j + 12] += z2[kk] * w3[j];
                    acc[3][j + 12] += z3[kk] * w3[j];
                }
            }
        }
#pragma unroll
        for (int i = 0; i < 4; ++i) {
            float* orow = out + (size_t)(node0 + ty * 4 + i) * 512 + tx * 16;
#pragma unroll
            for (int q = 0; q < 4; ++q) {
                v4 o;
#pragma unroll
                for (int m = 0; m < 4; ++m) o[m] = acc[i][q * 4 + m];
                *(v4*)&orow[q * 4] = o;
            }
        }
    }
}

extern "C" void kernel_launch(void* const* d_in, const int* in_sizes, int n_in,
                              void* d_out, int out_size, void* d_ws, size_t ws_size,
                              hipStream_t stream) {
    const float* x          = (const float*)d_in[0];
    const int*   edge_index = (const int*)d_in[1];
    const float* edge_attr  = (const float*)d_in[2];
    const float* u          = (const float*)d_in[3];
    const int*   batch      = (const int*)d_in[4];
    const float* W1a        = (const float*)d_in[5];
    const float* b1a        = (const float*)d_in[6];
    const float* W1b        = (const float*)d_in[7];
    const float* b1b        = (const float*)d_in[8];
    const float* W2a        = (const float*)d_in[9];
    const float* b2a        = (const float*)d_in[10];
    const float* W2b        = (const float*)d_in[11];
    const float* b2b        = (const float*)d_in[12];
    float* out = (float*)d_out;

    float* s   = (float*)d_ws;                 // [NN,128] sums
    float* cnt = s + (size_t)NN * 128;         // [NN] counts

    hipMemsetAsync(d_ws, 0, ((size_t)NN * 128 + NN) * sizeof(float), stream);

    edge_kernel<<<(NE + 511) / 512, 256, 0, stream>>>(
        x, edge_index, edge_attr, W1a, b1a, W1b, b1b, s, cnt);

    node_kernel<<<NN / 32, 256, 0, stream>>>(
        x, u, batch, s, cnt, W2a, b2a, W2b, b2b, out);
}

// Round 2
// 1709.817 us; speedup vs baseline: 4.8441x; 4.8441x over previous
//
#include <hip/hip_runtime.h>

#define NN 100000
#define NE 600000
#define NP 100096   // 391*256, padded node count
#define NB 391

typedef float v4 __attribute__((ext_vector_type(4)));

// ---------------------------------------------------------------------------
// CSR construction: histogram -> scan -> fill
// ---------------------------------------------------------------------------
__global__ __launch_bounds__(256) void hist_kernel(const int* __restrict__ ei,
                                                   int* __restrict__ deg) {
    int e = blockIdx.x * 256 + threadIdx.x;
    if (e < NE) atomicAdd(&deg[ei[e]], 1);
}

__global__ __launch_bounds__(256) void scan1_kernel(const int* __restrict__ deg,
                                                    int* __restrict__ partial,
                                                    int* __restrict__ bsum) {
    __shared__ int tmp[256];
    int t = threadIdx.x;
    int i = blockIdx.x * 256 + t;
    int v = deg[i];
    tmp[t] = v;
    __syncthreads();
    for (int off = 1; off < 256; off <<= 1) {
        int add = (t >= off) ? tmp[t - off] : 0;
        __syncthreads();
        tmp[t] += add;
        __syncthreads();
    }
    partial[i] = tmp[t] - v;          // exclusive within block
    if (t == 255) bsum[blockIdx.x] = tmp[255];
}

__global__ __launch_bounds__(512) void scan2_kernel(const int* __restrict__ bsum,
                                                    int* __restrict__ boff) {
    __shared__ int tmp[512];
    int t = threadIdx.x;
    int v = (t < NB) ? bsum[t] : 0;
    tmp[t] = v;
    __syncthreads();
    for (int off = 1; off < 512; off <<= 1) {
        int add = (t >= off) ? tmp[t - off] : 0;
        __syncthreads();
        tmp[t] += add;
        __syncthreads();
    }
    boff[t] = tmp[t] - v;             // exclusive across blocks
}

__global__ __launch_bounds__(256) void scan3_kernel(const int* __restrict__ partial,
                                                    const int* __restrict__ boff,
                                                    int* __restrict__ base,
                                                    int* __restrict__ cursor) {
    int i = blockIdx.x * 256 + threadIdx.x;
    int b = partial[i] + boff[blockIdx.x];
    base[i] = b;
    cursor[i] = b;
}

__global__ __launch_bounds__(256) void fill_kernel(const int* __restrict__ ei,
                                                   int* __restrict__ cursor,
                                                   int* __restrict__ csr) {
    int e = blockIdx.x * 256 + threadIdx.x;
    if (e < NE) {
        int r = ei[e];
        int p = atomicAdd(&cursor[r], 1);
        csr[p] = e;
    }
}

// ---------------------------------------------------------------------------
// Fused gather: one thread per node; recompute edge MLP per incoming edge,
// accumulate mean in registers, write agg[n][128]. Two 64-col half passes
// keep VGPRs low; 2 edges/iteration -> 8 FMA per LDS b128 broadcast read.
// agg = (sum_e h1_e @ W1b)/d + b1b  for d>0, else 0.
// ---------------------------------------------------------------------------
__global__ __launch_bounds__(256) void agg_kernel(
    const float* __restrict__ x, const int* __restrict__ ei,
    const float* __restrict__ ea,
    const float* __restrict__ W1a, const float* __restrict__ b1a,
    const float* __restrict__ W1b, const float* __restrict__ b1b,
    const int* __restrict__ base, const int* __restrict__ deg,
    const int* __restrict__ csr, float* __restrict__ agg)
{
    __shared__ float w1a[256];
    __shared__ float ba[64];
    __shared__ float w1b[8192];
    __shared__ float bb[128];
    const int tid = threadIdx.x;

    w1a[tid] = W1a[tid];
    if (tid < 64)  ba[tid] = b1a[tid];
    if (tid < 128) bb[tid] = b1b[tid];
    for (int i = tid * 4; i < 8192; i += 1024)
        *(v4*)&w1b[i] = *(const v4*)&W1b[i];
    __syncthreads();

    const int n = blockIdx.x * 256 + tid;
    const bool act = n < NN;
    const int d  = act ? deg[n]  : 0;
    const int b0 = act ? base[n] : 0;

    for (int hh = 0; hh < 2; ++hh) {
        float acc[64];
#pragma unroll
        for (int c = 0; c < 64; ++c) acc[c] = 0.f;

        for (int i = 0; i < d; i += 2) {
            int eA = csr[b0 + i];
            bool vB = (i + 1) < d;
            int eB = vB ? csr[b0 + i + 1] : eA;
            int colA = ei[NE + eA], colB = ei[NE + eB];
            float inA0 = x[2 * colA], inA1 = x[2 * colA + 1];
            float inA2 = ea[2 * eA],  inA3 = ea[2 * eA + 1];
            float inB0 = x[2 * colB], inB1 = x[2 * colB + 1];
            float inB2 = ea[2 * eB],  inB3 = ea[2 * eB + 1];

            for (int kg = 0; kg < 16; ++kg) {   // dynamic: h1 built 4-at-a-time
                v4 r0 = *(const v4*)&w1a[0 * 64 + kg * 4];
                v4 r1 = *(const v4*)&w1a[1 * 64 + kg * 4];
                v4 r2 = *(const v4*)&w1a[2 * 64 + kg * 4];
                v4 r3 = *(const v4*)&w1a[3 * 64 + kg * 4];
                v4 b4 = *(const v4*)&ba[kg * 4];
                v4 ha, hb;
#pragma unroll
                for (int m = 0; m < 4; ++m) {
                    float a_ = b4[m] + inA0 * r0[m] + inA1 * r1[m]
                                     + inA2 * r2[m] + inA3 * r3[m];
                    float b_ = b4[m] + inB0 * r0[m] + inB1 * r1[m]
                                     + inB2 * r2[m] + inB3 * r3[m];
                    ha[m] = fmaxf(a_, 0.f);
                    hb[m] = vB ? fmaxf(b_, 0.f) : 0.f;
                }
                const float* wrow = &w1b[(kg * 4) * 128 + hh * 64];
#pragma unroll
                for (int kk = 0; kk < 4; ++kk) {
#pragma unroll
                    for (int cg = 0; cg < 16; ++cg) {
                        v4 w = *(const v4*)&wrow[kk * 128 + cg * 4];
#pragma unroll
                        for (int m = 0; m < 4; ++m)
                            acc[cg * 4 + m] += ha[kk] * w[m] + hb[kk] * w[m];
                    }
                }
            }
        }

        if (act) {
            float inv = (d > 0) ? 1.0f / (float)d : 0.f;
#pragma unroll
            for (int cg = 0; cg < 16; ++cg) {
                v4 o;
#pragma unroll
                for (int m = 0; m < 4; ++m) {
                    int c = cg * 4 + m;
                    o[m] = (d > 0) ? (acc[c] * inv + bb[hh * 64 + c]) : 0.f;
                }
                *(v4*)&agg[(size_t)n * 128 + hh * 64 + cg * 4] = o;
            }
        }
    }
}

// ---------------------------------------------------------------------------
// Node kernel: z = [x, agg, u[batch]]; out = relu(z@W2a+b2a)@W2b+b2b
// 32 nodes per block, 256 threads. fp32 register tiling. (unchanged R1 core)
// ---------------------------------------------------------------------------
__global__ __launch_bounds__(256) void node_kernel(
    const float* __restrict__ x, const float* __restrict__ u,
    const int* __restrict__ batch,
    const float* __restrict__ agg,
    const float* __restrict__ W2a, const float* __restrict__ b2a,
    const float* __restrict__ W2b, const float* __restrict__ b2b,
    float* __restrict__ out)
{
    __shared__ float zs[32][136];
    __shared__ float ts[32][260];
    const int tid = threadIdx.x;
    const int node0 = blockIdx.x * 32;

    for (int idx = tid; idx < 32 * 132; idx += 256) {
        int r = idx / 132;
        int k = idx - r * 132;
        int node = node0 + r;
        float v;
        if (k < 2) {
            v = x[node * 2 + k];
        } else if (k < 130) {
            v = agg[(size_t)node * 128 + (k - 2)];
        } else {
            v = u[batch[node] * 2 + (k - 130)];
        }
        zs[r][k] = v;
    }
    __syncthreads();

    const int tx = tid & 31;
    const int ty = tid >> 5;

    // Phase B: t = relu(z @ W2a + b2a)
    {
        float acc[4][8];
#pragma unroll
        for (int j = 0; j < 8; ++j) {
            float bj = b2a[tx * 8 + j];
            acc[0][j] = bj; acc[1][j] = bj; acc[2][j] = bj; acc[3][j] = bj;
        }
        for (int k = 0; k < 132; k += 4) {
            v4 z0 = *(const v4*)&zs[ty * 4 + 0][k];
            v4 z1 = *(const v4*)&zs[ty * 4 + 1][k];
            v4 z2 = *(const v4*)&zs[ty * 4 + 2][k];
            v4 z3 = *(const v4*)&zs[ty * 4 + 3][k];
#pragma unroll
            for (int kk = 0; kk < 4; ++kk) {
                v4 w0 = *(const v4*)&W2a[(k + kk) * 256 + tx * 8];
                v4 w1 = *(const v4*)&W2a[(k + kk) * 256 + tx * 8 + 4];
#pragma unroll
                for (int j = 0; j < 4; ++j) {
                    acc[0][j]     += z0[kk] * w0[j];
                    acc[1][j]     += z1[kk] * w0[j];
                    acc[2][j]     += z2[kk] * w0[j];
                    acc[3][j]     += z3[kk] * w0[j];
                    acc[0][j + 4] += z0[kk] * w1[j];
                    acc[1][j + 4] += z1[kk] * w1[j];
                    acc[2][j + 4] += z2[kk] * w1[j];
                    acc[3][j + 4] += z3[kk] * w1[j];
                }
            }
        }
#pragma unroll
        for (int i = 0; i < 4; ++i) {
            v4 o0, o1;
#pragma unroll
            for (int j = 0; j < 4; ++j) {
                o0[j] = fmaxf(acc[i][j], 0.f);
                o1[j] = fmaxf(acc[i][j + 4], 0.f);
            }
            *(v4*)&ts[ty * 4 + i][tx * 8] = o0;
            *(v4*)&ts[ty * 4 + i][tx * 8 + 4] = o1;
        }
    }
    __syncthreads();

    // Phase C: out = ts @ W2b + b2b
    {
        float acc[4][16];
#pragma unroll
        for (int j = 0; j < 16; ++j) {
            float bj = b2b[tx * 16 + j];
            acc[0][j] = bj; acc[1][j] = bj; acc[2][j] = bj; acc[3][j] = bj;
        }
        for (int k = 0; k < 256; k += 4) {
            v4 z0 = *(const v4*)&ts[ty * 4 + 0][k];
            v4 z1 = *(const v4*)&ts[ty * 4 + 1][k];
            v4 z2 = *(const v4*)&ts[ty * 4 + 2][k];
            v4 z3 = *(const v4*)&ts[ty * 4 + 3][k];
#pragma unroll
            for (int kk = 0; kk < 4; ++kk) {
                v4 w0 = *(const v4*)&W2b[(k + kk) * 512 + tx * 16];
                v4 w1 = *(const v4*)&W2b[(k + kk) * 512 + tx * 16 + 4];
                v4 w2 = *(const v4*)&W2b[(k + kk) * 512 + tx * 16 + 8];
                v4 w3 = *(const v4*)&W2b[(k + kk) * 512 + tx * 16 + 12];
#pragma unroll
                for (int j = 0; j < 4; ++j) {
                    acc[0][j]      += z0[kk] * w0[j];
                    acc[1][j]      += z1[kk] * w0[j];
                    acc[2][j]      += z2[kk] * w0[j];
                    acc[3][j]      += z3[kk] * w0[j];
                    acc[0][j + 4]  += z0[kk] * w1[j];
                    acc[1][j + 4]  += z1[kk] * w1[j];
                    acc[2][j + 4]  += z2[kk] * w1[j];
                    acc[3][j + 4]  += z3[kk] * w1[j];
                    acc[0][j + 8]  += z0[kk] * w2[j];
                    acc[1][j + 8]  += z1[kk] * w2[j];
                    acc[2][j + 8]  += z2[kk] * w2[j];
                    acc[3][j + 8]  += z3[kk] * w2[j];
                    acc[0][j + 12] += z0[kk] * w3[j];
                    acc[1][j + 12] += z1[kk] * w3[j];
                    acc[2][j + 12] += z2[kk] * w3[j];
                    acc[3][j + 12] += z3[kk] * w3[j];
                }
            }
        }
#pragma unroll
        for (int i = 0; i < 4; ++i) {
            float* orow = out + (size_t)(node0 + ty * 4 + i) * 512 + tx * 16;
#pragma unroll
            for (int q = 0; q < 4; ++q) {
                v4 o;
#pragma unroll
                for (int m = 0; m < 4; ++m) o[m] = acc[i][q * 4 + m];
                *(v4*)&orow[q * 4] = o;
            }
        }
    }
}

extern "C" void kernel_launch(void* const* d_in, const int* in_sizes, int n_in,
                              void* d_out, int out_size, void* d_ws, size_t ws_size,
                              hipStream_t stream) {
    const float* x          = (const float*)d_in[0];
    const int*   edge_index = (const int*)d_in[1];
    const float* edge_attr  = (const float*)d_in[2];
    const float* u          = (const float*)d_in[3];
    const int*   batch      = (const int*)d_in[4];
    const float* W1a        = (const float*)d_in[5];
    const float* b1a        = (const float*)d_in[6];
    const float* W1b        = (const float*)d_in[7];
    const float* b1b        = (const float*)d_in[8];
    const float* W2a        = (const float*)d_in[9];
    const float* b2a        = (const float*)d_in[10];
    const float* W2b        = (const float*)d_in[11];
    const float* b2b        = (const float*)d_in[12];
    float* out = (float*)d_out;

    // workspace layout
    float* agg    = (float*)d_ws;                       // [NN,128]
    int*   deg    = (int*)(agg + (size_t)NN * 128);     // [NP]
    int*   partial= deg + NP;                           // [NP]
    int*   bsum   = partial + NP;                       // [512]
    int*   boff   = bsum + 512;                         // [512]
    int*   base   = boff + 512;                         // [NP]
    int*   cursor = base + NP;                          // [NP]
    int*   csr    = cursor + NP;                        // [NE]

    hipMemsetAsync(deg, 0, NP * sizeof(int), stream);

    hist_kernel <<<(NE + 255) / 256, 256, 0, stream>>>(edge_index, deg);
    scan1_kernel<<<NB, 256, 0, stream>>>(deg, partial, bsum);
    scan2_kernel<<<1, 512, 0, stream>>>(bsum, boff);
    scan3_kernel<<<NB, 256, 0, stream>>>(partial, boff, base, cursor);
    fill_kernel <<<(NE + 255) / 256, 256, 0, stream>>>(edge_index, cursor, csr);

    agg_kernel<<<NB, 256, 0, stream>>>(
        x, edge_index, edge_attr, W1a, b1a, W1b, b1b, base, deg, csr, agg);

    node_kernel<<<NN / 32, 256, 0, stream>>>(
        x, u, batch, agg, W2a, b2a, W2b, b2b, out);
}

// Round 5
// 955.073 us; speedup vs baseline: 8.6721x; 1.7902x over previous
//
#include <hip/hip_runtime.h>

#define NN 100000
#define NE 600000
#define NP 100096   // 391*256, padded node count
#define NB 391

typedef float v4    __attribute__((ext_vector_type(4)));
typedef float f32x4 __attribute__((ext_vector_type(4)));
typedef short s16x4 __attribute__((ext_vector_type(4)));
typedef short s16x8 __attribute__((ext_vector_type(8)));

__device__ __forceinline__ short f2bf(float f) {
    unsigned u = __float_as_uint(f);
    u = (u + 0x7fffu + ((u >> 16) & 1u)) >> 16;
    return (short)u;
}

// ---------------------------------------------------------------------------
// CSR construction: histogram -> scan -> fill  (unchanged from R2)
// ---------------------------------------------------------------------------
__global__ __launch_bounds__(256) void hist_kernel(const int* __restrict__ ei,
                                                   int* __restrict__ deg) {
    int e = blockIdx.x * 256 + threadIdx.x;
    if (e < NE) atomicAdd(&deg[ei[e]], 1);
}

__global__ __launch_bounds__(256) void scan1_kernel(const int* __restrict__ deg,
                                                    int* __restrict__ partial,
                                                    int* __restrict__ bsum) {
    __shared__ int tmp[256];
    int t = threadIdx.x;
    int i = blockIdx.x * 256 + t;
    int v = deg[i];
    tmp[t] = v;
    __syncthreads();
    for (int off = 1; off < 256; off <<= 1) {
        int add = (t >= off) ? tmp[t - off] : 0;
        __syncthreads();
        tmp[t] += add;
        __syncthreads();
    }
    partial[i] = tmp[t] - v;
    if (t == 255) bsum[blockIdx.x] = tmp[255];
}

__global__ __launch_bounds__(512) void scan2_kernel(const int* __restrict__ bsum,
                                                    int* __restrict__ boff) {
    __shared__ int tmp[512];
    int t = threadIdx.x;
    int v = (t < NB) ? bsum[t] : 0;
    tmp[t] = v;
    __syncthreads();
    for (int off = 1; off < 512; off <<= 1) {
        int add = (t >= off) ? tmp[t - off] : 0;
        __syncthreads();
        tmp[t] += add;
        __syncthreads();
    }
    boff[t] = tmp[t] - v;
}

__global__ __launch_bounds__(256) void scan3_kernel(const int* __restrict__ partial,
                                                    const int* __restrict__ boff,
                                                    int* __restrict__ base,
                                                    int* __restrict__ cursor) {
    int i = blockIdx.x * 256 + threadIdx.x;
    int b = partial[i] + boff[blockIdx.x];
    base[i] = b;
    cursor[i] = b;
}

__global__ __launch_bounds__(256) void fill_kernel(const int* __restrict__ ei,
                                                   int* __restrict__ cursor,
                                                   int* __restrict__ csr) {
    int e = blockIdx.x * 256 + threadIdx.x;
    if (e < NE) {
        int r = ei[e];
        int p = atomicAdd(&cursor[r], 1);
        csr[p] = e;
    }
}

// ---------------------------------------------------------------------------
// Weight prep: W2aT [256][160] bf16 with z-reorder [agg(128), x(2), u(2), 0*28]
//              W2bT [512][256] bf16   (both B^T layout: [N][K], K contiguous)
// ---------------------------------------------------------------------------
__global__ __launch_bounds__(256) void prep_kernel(const float* __restrict__ W2a,
                                                   const float* __restrict__ W2b,
                                                   short* __restrict__ W2aT,
                                                   short* __restrict__ W2bT) {
    int idx = blockIdx.x * 256 + threadIdx.x;
    if (idx < 256 * 160) {
        int n = idx / 160, k = idx - n * 160;
        float v = 0.f;
        if (k < 128)       v = W2a[(2 + k) * 256 + n];
        else if (k == 128) v = W2a[0 * 256 + n];
        else if (k == 129) v = W2a[1 * 256 + n];
        else if (k == 130) v = W2a[130 * 256 + n];
        else if (k == 131) v = W2a[131 * 256 + n];
        W2aT[idx] = f2bf(v);
    }
    if (idx < 512 * 256) {
        int n = idx >> 8, k = idx & 255;
        W2bT[idx] = f2bf(W2b[k * 512 + n]);
    }
}

// ---------------------------------------------------------------------------
// Fused gather agg kernel (unchanged from R2)
// ---------------------------------------------------------------------------
__global__ __launch_bounds__(256) void agg_kernel(
    const float* __restrict__ x, const int* __restrict__ ei,
    const float* __restrict__ ea,
    const float* __restrict__ W1a, const float* __restrict__ b1a,
    const float* __restrict__ W1b, const float* __restrict__ b1b,
    const int* __restrict__ base, const int* __restrict__ deg,
    const int* __restrict__ csr, float* __restrict__ agg)
{
    __shared__ float w1a[256];
    __shared__ float ba[64];
    __shared__ float w1b[8192];
    __shared__ float bb[128];
    const int tid = threadIdx.x;

    w1a[tid] = W1a[tid];
    if (tid < 64)  ba[tid] = b1a[tid];
    if (tid < 128) bb[tid] = b1b[tid];
    for (int i = tid * 4; i < 8192; i += 1024)
        *(v4*)&w1b[i] = *(const v4*)&W1b[i];
    __syncthreads();

    const int n = blockIdx.x * 256 + tid;
    const bool act = n < NN;
    const int d  = act ? deg[n]  : 0;
    const int b0 = act ? base[n] : 0;

    for (int hh = 0; hh < 2; ++hh) {
        float acc[64];
#pragma unroll
        for (int c = 0; c < 64; ++c) acc[c] = 0.f;

        for (int i = 0; i < d; i += 2) {
            int eA = csr[b0 + i];
            bool vB = (i + 1) < d;
            int eB = vB ? csr[b0 + i + 1] : eA;
            int colA = ei[NE + eA], colB = ei[NE + eB];
            float inA0 = x[2 * colA], inA1 = x[2 * colA + 1];
            float inA2 = ea[2 * eA],  inA3 = ea[2 * eA + 1];
            float inB0 = x[2 * colB], inB1 = x[2 * colB + 1];
            float inB2 = ea[2 * eB],  inB3 = ea[2 * eB + 1];

            for (int kg = 0; kg < 16; ++kg) {
                v4 r0 = *(const v4*)&w1a[0 * 64 + kg * 4];
                v4 r1 = *(const v4*)&w1a[1 * 64 + kg * 4];
                v4 r2 = *(const v4*)&w1a[2 * 64 + kg * 4];
                v4 r3 = *(const v4*)&w1a[3 * 64 + kg * 4];
                v4 b4 = *(const v4*)&ba[kg * 4];
                v4 ha, hb;
#pragma unroll
                for (int m = 0; m < 4; ++m) {
                    float a_ = b4[m] + inA0 * r0[m] + inA1 * r1[m]
                                     + inA2 * r2[m] + inA3 * r3[m];
                    float b_ = b4[m] + inB0 * r0[m] + inB1 * r1[m]
                                     + inB2 * r2[m] + inB3 * r3[m];
                    ha[m] = fmaxf(a_, 0.f);
                    hb[m] = vB ? fmaxf(b_, 0.f) : 0.f;
                }
                const float* wrow = &w1b[(kg * 4) * 128 + hh * 64];
#pragma unroll
                for (int kk = 0; kk < 4; ++kk) {
#pragma unroll
                    for (int cg = 0; cg < 16; ++cg) {
                        v4 w = *(const v4*)&wrow[kk * 128 + cg * 4];
#pragma unroll
                        for (int m = 0; m < 4; ++m)
                            acc[cg * 4 + m] += ha[kk] * w[m] + hb[kk] * w[m];
                    }
                }
            }
        }

        if (act) {
            float inv = (d > 0) ? 1.0f / (float)d : 0.f;
#pragma unroll
            for (int cg = 0; cg < 16; ++cg) {
                v4 o;
#pragma unroll
                for (int m = 0; m < 4; ++m) {
                    int c = cg * 4 + m;
                    o[m] = (d > 0) ? (acc[c] * inv + bb[hh * 64 + c]) : 0.f;
                }
                *(v4*)&agg[(size_t)n * 128 + hh * 64 + cg * 4] = o;
            }
        }
    }
}

// ---------------------------------------------------------------------------
// Node MFMA kernel: 64 nodes/block, 512 threads (8 waves).
// z' = [agg(128), x(2), u(2), pad->160] bf16 in LDS (XOR chunk swizzle).
// L1: t = relu(z'@W2a'+b2a)  K=160, N=256 -> tb (bf16, swizzled)
// L2: out = t@W2b+b2b        K=256, N=512 -> global fp32
// Frags: A[m=lane&15][k=(lane>>4)*8+j], B[n=lane&15][k=(lane>>4)*8+j] (B^T)
// ---------------------------------------------------------------------------
__global__ __launch_bounds__(512, 2) void node_mfma_kernel(
    const float* __restrict__ x, const float* __restrict__ u,
    const int* __restrict__ batch,
    const float* __restrict__ agg,
    const short* __restrict__ W2aT, const short* __restrict__ W2bT,
    const float* __restrict__ b2a, const float* __restrict__ b2b,
    float* __restrict__ out)
{
    __shared__ short zb[64 * 192];   // 64 rows x 24 chunks(16B): 160 cols + pad
    __shared__ short tb[64 * 256];   // 64 rows x 32 chunks: 256 cols
    const int tid = threadIdx.x;
    const int node0 = blockIdx.x * 64;

    // ---- stage agg -> zb cols 0..127 (coalesced f32x4, bf16 pack, swizzled)
#pragma unroll
    for (int it = 0; it < 4; ++it) {
        int idx = it * 512 + tid;         // 2048 = 64 rows * 32 f32x4-chunks
        int r = idx >> 5, c = idx & 31;
        int node = node0 + r;
        f32x4 v = {0.f, 0.f, 0.f, 0.f};
        if (node < NN) v = *(const f32x4*)&agg[(size_t)node * 128 + c * 4];
        s16x4 p;
        p[0] = f2bf(v[0]); p[1] = f2bf(v[1]); p[2] = f2bf(v[2]); p[3] = f2bf(v[3]);
        int ch = c >> 1;
        int sw = (ch & ~7) | ((ch ^ r) & 7);
        *(s16x4*)&zb[r * 192 + sw * 8 + (c & 1) * 4] = p;
    }
    // ---- chunk 16: [x0,x1,u0,u1,0,0,0,0]; chunks 17..19: zeros
    if (tid < 64) {
        int r = tid, node = node0 + r;
        s16x8 p = {0, 0, 0, 0, 0, 0, 0, 0};
        if (node < NN) {
            p[0] = f2bf(x[node * 2]); p[1] = f2bf(x[node * 2 + 1]);
            int b = batch[node];
            p[2] = f2bf(u[b * 2]); p[3] = f2bf(u[b * 2 + 1]);
        }
        int sw = 16 | (r & 7);
        *(s16x8*)&zb[r * 192 + sw * 8] = p;
    } else if (tid < 256) {
        int t2 = tid - 64;
        int r = t2 & 63;
        int ch = 17 + (t2 >> 6);
        int sw = (ch & ~7) | ((ch ^ r) & 7);
        s16x8 zz = {0, 0, 0, 0, 0, 0, 0, 0};
        *(s16x8*)&zb[r * 192 + sw * 8] = zz;
    }
    __syncthreads();

    const int lane = tid & 63, wid = tid >> 6;
    const int l15 = lane & 15, lk = lane >> 4;
    const int nw = wid;   // 8 waves: L1 cols nw*32, L2 cols nw*64; all 64 rows

    // ---- layer 1: K=160 (5 ksteps), per wave 4 mfrag x 2 nfrag
    f32x4 acc1[4][2];
#pragma unroll
    for (int mf = 0; mf < 4; ++mf)
#pragma unroll
        for (int nf = 0; nf < 2; ++nf)
            acc1[mf][nf] = (f32x4){0.f, 0.f, 0.f, 0.f};

#pragma unroll
    for (int ks = 0; ks < 5; ++ks) {
        s16x8 a[4], b[2];
        int cb = ks * 4 + lk;
#pragma unroll
        for (int mf = 0; mf < 4; ++mf) {
            int r = mf * 16 + l15;
            int sw = (cb & ~7) | ((cb ^ r) & 7);
            a[mf] = *(const s16x8*)&zb[r * 192 + sw * 8];
        }
#pragma unroll
        for (int nf = 0; nf < 2; ++nf) {
            int n = nw * 32 + nf * 16 + l15;
            b[nf] = *(const s16x8*)&W2aT[n * 160 + ks * 32 + lk * 8];
        }
#pragma unroll
        for (int mf = 0; mf < 4; ++mf)
#pragma unroll
            for (int nf = 0; nf < 2; ++nf)
                acc1[mf][nf] = __builtin_amdgcn_mfma_f32_16x16x32_bf16(
                    a[mf], b[nf], acc1[mf][nf], 0, 0, 0);
    }

    // ---- epilogue 1: bias + relu -> tb (bf16, swizzled). D: row=(lane>>4)*4+j, col=lane&15
#pragma unroll
    for (int nf = 0; nf < 2; ++nf) {
        int n = nw * 32 + nf * 16 + l15;
        float bias = b2a[n];
        int ch = n >> 3, off = n & 7;
#pragma unroll
        for (int mf = 0; mf < 4; ++mf) {
#pragma unroll
            for (int j = 0; j < 4; ++j) {
                int r = mf * 16 + lk * 4 + j;
                float vv = fmaxf(acc1[mf][nf][j] + bias, 0.f);
                int sw = (ch & ~7) | ((ch ^ r) & 7);
                tb[r * 256 + sw * 8 + off] = f2bf(vv);
            }
        }
    }
    __syncthreads();

    // ---- layer 2: K=256 (8 ksteps), per wave 4 mfrag x 4 nfrag (64 cols)
    f32x4 acc2[4][4];
#pragma unroll
    for (int mf = 0; mf < 4; ++mf)
#pragma unroll
        for (int nf = 0; nf < 4; ++nf)
            acc2[mf][nf] = (f32x4){0.f, 0.f, 0.f, 0.f};

#pragma unroll
    for (int ks = 0; ks < 8; ++ks) {
        s16x8 a[4], b[4];
        int cb = ks * 4 + lk;
#pragma unroll
        for (int mf = 0; mf < 4; ++mf) {
            int r = mf * 16 + l15;
            int sw = (cb & ~7) | ((cb ^ r) & 7);
            a[mf] = *(const s16x8*)&tb[r * 256 + sw * 8];
        }
#pragma unroll
        for (int nf = 0; nf < 4; ++nf) {
            int n = nw * 64 + nf * 16 + l15;
            b[nf] = *(const s16x8*)&W2bT[n * 256 + ks * 32 + lk * 8];
        }
#pragma unroll
        for (int mf = 0; mf < 4; ++mf)
#pragma unroll
            for (int nf = 0; nf < 4; ++nf)
                acc2[mf][nf] = __builtin_amdgcn_mfma_f32_16x16x32_bf16(
                    a[mf], b[nf], acc2[mf][nf], 0, 0, 0);
    }

    // ---- epilogue 2: bias + store fp32
#pragma unroll
    for (int nf = 0; nf < 4; ++nf) {
        int n = nw * 64 + nf * 16 + l15;
        float bias = b2b[n];
#pragma unroll
        for (int mf = 0; mf < 4; ++mf) {
#pragma unroll
            for (int j = 0; j < 4; ++j) {
                int r = mf * 16 + lk * 4 + j;
                int node = node0 + r;
                if (node < NN)
                    out[(size_t)node * 512 + n] = acc2[mf][nf][j] + bias;
            }
        }
    }
}

extern "C" void kernel_launch(void* const* d_in, const int* in_sizes, int n_in,
                              void* d_out, int out_size, void* d_ws, size_t ws_size,
                              hipStream_t stream) {
    const float* x          = (const float*)d_in[0];
    const int*   edge_index = (const int*)d_in[1];
    const float* edge_attr  = (const float*)d_in[2];
    const float* u          = (const float*)d_in[3];
    const int*   batch      = (const int*)d_in[4];
    const float* W1a        = (const float*)d_in[5];
    const float* b1a        = (const float*)d_in[6];
    const float* W1b        = (const float*)d_in[7];
    const float* b1b        = (const float*)d_in[8];
    const float* W2a        = (const float*)d_in[9];
    const float* b2a        = (const float*)d_in[10];
    const float* W2b        = (const float*)d_in[11];
    const float* b2b        = (const float*)d_in[12];
    float* out = (float*)d_out;

    // workspace layout
    float* agg    = (float*)d_ws;                        // [NN,128] fp32
    short* W2aT   = (short*)(agg + (size_t)NN * 128);    // [256,160] bf16
    short* W2bT   = W2aT + 256 * 160;                    // [512,256] bf16
    int*   deg    = (int*)(W2bT + 512 * 256);            // [NP]
    int*   partial= deg + NP;                            // [NP]
    int*   bsum   = partial + NP;                        // [512]
    int*   boff   = bsum + 512;                          // [512]
    int*   base   = boff + 512;                          // [NP]
    int*   cursor = base + NP;                           // [NP]
    int*   csr    = cursor + NP;                         // [NE]

    hipMemsetAsync(deg, 0, NP * sizeof(int), stream);

    prep_kernel <<<512, 256, 0, stream>>>(W2a, W2b, W2aT, W2bT);
    hist_kernel <<<(NE + 255) / 256, 256, 0, stream>>>(edge_index, deg);
    scan1_kernel<<<NB, 256, 0, stream>>>(deg, partial, bsum);
    scan2_kernel<<<1, 512, 0, stream>>>(bsum, boff);
    scan3_kernel<<<NB, 256, 0, stream>>>(partial, boff, base, cursor);
    fill_kernel <<<(NE + 255) / 256, 256, 0, stream>>>(edge_index, cursor, csr);

    agg_kernel<<<NB, 256, 0, stream>>>(
        x, edge_index, edge_attr, W1a, b1a, W1b, b1b, base, deg, csr, agg);

    node_mfma_kernel<<<(NN + 63) / 64, 512, 0, stream>>>(
        x, u, batch, agg, W2aT, W2bT, b2a, b2b, out);
}